// Round 13
// baseline (231.936 us; speedup 1.0000x reference)
//
#include <hip/hip_runtime.h>

// Problem constants: N=50000, E=800000, IN=128, HID=64, OUT=40
#define HID 64
#define JK_DIM 192
#define OUT_DIM 40
#define AP 136         // bf16 LDS pitch for 128-wide tiles (272B = 16B-aligned)
#define HP 72          // bf16 LDS pitch for 64-wide tiles (144B = 16B-aligned)

typedef __attribute__((ext_vector_type(8))) short bf16x8;
typedef __attribute__((ext_vector_type(4))) float f32x4;

// bf16 helpers (RNE pack; packed-word unpack via shift/mask)
__device__ inline unsigned short f2b(float f) {
    unsigned u = __float_as_uint(f);
    unsigned r = u + 0x7FFF + ((u >> 16) & 1);
    return (unsigned short)(r >> 16);
}
__device__ inline float b2f(unsigned short u) {
    return __uint_as_float(((unsigned)u) << 16);
}
__device__ inline float blo(unsigned u) { return __uint_as_float(u << 16); }
__device__ inline float bhi(unsigned u) { return __uint_as_float(u & 0xFFFF0000u); }
__device__ inline unsigned pack2(float a, float b) {
    return (unsigned)f2b(a) | ((unsigned)f2b(b) << 16);
}

// ---------------------------------------------------------------------------
// hist_dst: XCD-partitioned histogram + edge arrival rank (atomic-free fill).
// Blocks [0, histBlk): histogram. Blocks [histBlk, histBlk+32): bf16 weight
// transposes. deg/gctr zeroing is a memset.
// ---------------------------------------------------------------------------
__global__ __launch_bounds__(256) void hist_dst(const int* __restrict__ dst,
                                                int* __restrict__ deg,
                                                unsigned short* __restrict__ rank,
                                                int E, int part, int histBlk,
                                                const float* __restrict__ W1,
                                                const float* __restrict__ W2,
                                                const float* __restrict__ W3,
                                                const float* __restrict__ Wlin,
                                                unsigned short* __restrict__ W1T,
                                                unsigned short* __restrict__ W2T,
                                                unsigned short* __restrict__ W3T,
                                                unsigned short* __restrict__ WlinT) {
    if ((int)blockIdx.x >= histBlk) {
        int base = (blockIdx.x - histBlk) * 256 + threadIdx.x;
        int stride = 32 * 256;
        for (int i = base; i < 64 * 128; i += stride) {
            int nn = i >> 7, k = i & 127;
            W1T[i] = f2b(W1[k * 64 + nn]);
        }
        for (int i = base; i < 64 * 64; i += stride) {
            int nn = i >> 6, k = i & 63;
            W2T[i] = f2b(W2[k * 64 + nn]);
            W3T[i] = f2b(W3[k * 64 + nn]);
        }
        for (int i = base; i < 48 * JK_DIM; i += stride) {
            int c = i / JK_DIM, k = i - c * JK_DIM;
            WlinT[i] = (c < OUT_DIM) ? f2b(Wlin[k * OUT_DIM + c]) : (unsigned short)0;
        }
        return;
    }
    int p = blockIdx.x & 7;
    int bid = blockIdx.x >> 3;
    int nblk = histBlk >> 3;
    int lo = p * part, hi = lo + part;
    int E4 = E >> 2;
    for (int q = bid * 256 + threadIdx.x; q < E4; q += nblk * 256) {
        int4 d4 = ((const int4*)dst)[q];
        int e = q * 4;
        if (d4.x >= lo && d4.x < hi) rank[e + 0] = (unsigned short)atomicAdd(&deg[d4.x], 1);
        if (d4.y >= lo && d4.y < hi) rank[e + 1] = (unsigned short)atomicAdd(&deg[d4.y], 1);
        if (d4.z >= lo && d4.z < hi) rank[e + 2] = (unsigned short)atomicAdd(&deg[d4.z], 1);
        if (d4.w >= lo && d4.w < hi) rank[e + 3] = (unsigned short)atomicAdd(&deg[d4.w], 1);
    }
    if (bid == 0 && threadIdx.x < (E & 3)) {
        int e = (E & ~3) + threadIdx.x;
        int d = dst[e];
        if (d >= lo && d < hi) rank[e] = (unsigned short)atomicAdd(&deg[d], 1);
    }
}

// ---------------------------------------------------------------------------
// Single-pass scan: block-local prefix + one atomicAdd per block for the base.
// ---------------------------------------------------------------------------
__global__ __launch_bounds__(256) void scan_fused(const int* __restrict__ deg,
                                                  int* __restrict__ off,
                                                  int* __restrict__ gctr, int n) {
    __shared__ int tmp[256];
    __shared__ int base;
    int i = blockIdx.x * 256 + threadIdx.x;
    int v = (i < n) ? deg[i] : 0;
    tmp[threadIdx.x] = v;
    __syncthreads();
    for (int d = 1; d < 256; d <<= 1) {
        int t = (threadIdx.x >= d) ? tmp[threadIdx.x - d] : 0;
        __syncthreads();
        tmp[threadIdx.x] += t;
        __syncthreads();
    }
    if (threadIdx.x == 255) base = atomicAdd(gctr, tmp[255]);
    __syncthreads();
    if (i < n) off[i] = base + tmp[threadIdx.x] - v;
}

// ---------------------------------------------------------------------------
// FUSED: atomic-free CSR fill + layer-1 GEMM (MFMA bf16, LDS-staged).
// ---------------------------------------------------------------------------
__global__ __launch_bounds__(256) void fill_and_gemm(
        const int* __restrict__ src, const int* __restrict__ dst,
        const float* __restrict__ ew, const int* __restrict__ off,
        const unsigned short* __restrict__ rank,
        unsigned* __restrict__ ecsr, int E,
        const float* __restrict__ x, const unsigned short* __restrict__ W1T,
        unsigned short* __restrict__ linb, int n, int nFill) {
    __shared__ unsigned short Ah[64 * AP];   // A tile, bf16
    __shared__ unsigned short Wt[64 * AP];   // W1^T tile, bf16
    int tid = threadIdx.x;
    if ((int)blockIdx.x < nFill) {
        int q = blockIdx.x * 256 + tid;
        int E4 = E >> 2;
        if (q < E4) {
            int4 d4 = ((const int4*)dst)[q];
            int4 s4 = ((const int4*)src)[q];
            float4 wv = ((const float4*)ew)[q];
            ushort4 r4 = ((const ushort4*)rank)[q];
            ecsr[off[d4.x] + r4.x] = (unsigned)s4.x | ((unsigned)f2b(wv.x) << 16);
            ecsr[off[d4.y] + r4.y] = (unsigned)s4.y | ((unsigned)f2b(wv.y) << 16);
            ecsr[off[d4.z] + r4.z] = (unsigned)s4.z | ((unsigned)f2b(wv.z) << 16);
            ecsr[off[d4.w] + r4.w] = (unsigned)s4.w | ((unsigned)f2b(wv.w) << 16);
        }
        if (blockIdx.x == 0 && tid < (E & 3)) {
            int e = (E & ~3) + tid;
            int d = dst[e];
            ecsr[off[d] + rank[e]] = (unsigned)src[e] | ((unsigned)f2b(ew[e]) << 16);
        }
        return;
    }
    int row0 = (blockIdx.x - nFill) * 64;
    if (row0 >= n) return;
    for (int i = tid; i < 64 * 32; i += 256) {
        int r = i >> 5;
        int c4 = (i & 31) * 4;
        int grow = row0 + r;
        if (grow >= n) grow = n - 1;
        float4 v = *(const float4*)(x + (long)grow * 128 + c4);
        ushort4 o;
        o.x = f2b(v.x); o.y = f2b(v.y); o.z = f2b(v.z); o.w = f2b(v.w);
        *(ushort4*)(Ah + r * AP + c4) = o;
    }
    for (int i = tid; i < 64 * 16; i += 256) {
        int nn = i >> 4;
        int k8 = (i & 15) * 8;
        *(uint4*)(Wt + nn * AP + k8) = *(const uint4*)(W1T + nn * 128 + k8);
    }
    __syncthreads();

    int wave = tid >> 6;
    int lane = tid & 63;
    int lr = lane & 15;
    int lk = (lane >> 4) * 8;
    f32x4 acc[4];
#pragma unroll
    for (int nf = 0; nf < 4; ++nf) acc[nf] = (f32x4){0.f, 0.f, 0.f, 0.f};
#pragma unroll
    for (int k0 = 0; k0 < 128; k0 += 32) {
        bf16x8 a = *(const bf16x8*)(Ah + (wave * 16 + lr) * AP + k0 + lk);
#pragma unroll
        for (int nf = 0; nf < 4; ++nf) {
            bf16x8 b = *(const bf16x8*)(Wt + (nf * 16 + lr) * AP + k0 + lk);
            acc[nf] = __builtin_amdgcn_mfma_f32_16x16x32_bf16(a, b, acc[nf], 0, 0, 0);
        }
    }
    int mbase = wave * 16 + (lane >> 4) * 4;
#pragma unroll
    for (int nf = 0; nf < 4; ++nf) {
#pragma unroll
        for (int r = 0; r < 4; ++r) {
            int grow = row0 + mbase + r;
            if (grow < n)
                linb[(long)grow * HID + nf * 16 + lr] = f2b(acc[nf][r]);
        }
    }
}

// ---------------------------------------------------------------------------
// Aggregate + bias + ReLU (layer 1). 8-lane group per node; 8-deep pipeline.
// ---------------------------------------------------------------------------
__global__ __launch_bounds__(256) void aggregate(const unsigned short* __restrict__ linb,
                                                 const unsigned* __restrict__ ecsr,
                                                 const int* __restrict__ off,
                                                 const int* __restrict__ deg,
                                                 const float* __restrict__ bias,
                                                 unsigned short* __restrict__ hout, int n) {
    int cl = threadIdx.x & 7;
    float4 bLo = *(const float4*)(bias + cl * 8);
    float4 bHi = *(const float4*)(bias + cl * 8 + 4);
    int grp = (blockIdx.x * 256 + threadIdx.x) >> 3;
    int ngrp = (gridDim.x * 256) >> 3;
    for (int node = grp; node < n; node += ngrp) {
        int start = off[node];
        int cnt = deg[node];
        float acc[8];
#pragma unroll
        for (int i = 0; i < 8; ++i) acc[i] = 0.f;

        int s[8];
        float w[8];
#pragma unroll
        for (int t = 0; t < 8; ++t) {
            s[t] = 0; w[t] = 0.f;
            if (t < cnt) {
                unsigned m = ecsr[start + t];
                s[t] = (int)(m & 0xFFFFu);
                w[t] = b2f((unsigned short)(m >> 16));
            }
        }
        for (int bb = 0; bb < cnt; bb += 8) {
            int s2[8];
            float w2[8];
#pragma unroll
            for (int t = 0; t < 8; ++t) {
                int e = bb + 8 + t;
                s2[t] = 0; w2[t] = 0.f;
                if (e < cnt) {
                    unsigned m = ecsr[start + e];
                    s2[t] = (int)(m & 0xFFFFu);
                    w2[t] = b2f((unsigned short)(m >> 16));
                }
            }
            uint4 u[8];
#pragma unroll
            for (int t = 0; t < 8; ++t)
                u[t] = *(const uint4*)(linb + (long)s[t] * HID + cl * 8);
#pragma unroll
            for (int t = 0; t < 8; ++t) {
                acc[0] += blo(u[t].x) * w[t];
                acc[1] += bhi(u[t].x) * w[t];
                acc[2] += blo(u[t].y) * w[t];
                acc[3] += bhi(u[t].y) * w[t];
                acc[4] += blo(u[t].z) * w[t];
                acc[5] += bhi(u[t].z) * w[t];
                acc[6] += blo(u[t].w) * w[t];
                acc[7] += bhi(u[t].w) * w[t];
            }
#pragma unroll
            for (int t = 0; t < 8; ++t) { s[t] = s2[t]; w[t] = w2[t]; }
        }

        uint4 o;
        o.x = pack2(fmaxf(acc[0] + bLo.x, 0.f), fmaxf(acc[1] + bLo.y, 0.f));
        o.y = pack2(fmaxf(acc[2] + bLo.z, 0.f), fmaxf(acc[3] + bLo.w, 0.f));
        o.z = pack2(fmaxf(acc[4] + bHi.x, 0.f), fmaxf(acc[5] + bHi.y, 0.f));
        o.w = pack2(fmaxf(acc[6] + bHi.z, 0.f), fmaxf(acc[7] + bHi.w, 0.f));
        *(uint4*)(hout + (long)node * JK_DIM + cl * 8) = o;
    }
}

// ---------------------------------------------------------------------------
// Layer 2: h_out = relu((A.h_prev)@W + b). 512 THREADS: 64 gather groups x
// 1 node each (2x gather concurrency, halved wave-lockstep max(deg) path);
// MFMA split 8 waves x 2 fragments (mi=wave>>1, ni=(wave&1)*2+{0,1}).
// ---------------------------------------------------------------------------
__global__ __launch_bounds__(512) void agg_transform(
        const unsigned short* __restrict__ hprev,   // row stride JK_DIM
        const unsigned* __restrict__ ecsr,
        const int* __restrict__ off, const int* __restrict__ deg,
        const unsigned short* __restrict__ WT, const float* __restrict__ bias,
        unsigned short* __restrict__ hout, int n) { // row stride JK_DIM
    __shared__ unsigned short Hs[64 * HP];
    __shared__ unsigned short Wt[64 * HP];
    int tid = threadIdx.x;
    int row0 = blockIdx.x * 64;
    if (row0 >= n) return;
    for (int i = tid; i < 64 * 8; i += 512) {
        int nn = i >> 3;
        int k8 = (i & 7) * 8;
        *(uint4*)(Wt + nn * HP + k8) = *(const uint4*)(WT + nn * 64 + k8);
    }
    int cl = tid & 7;
    int lrow = tid >> 3;           // 0..63, one node per 8-lane group
    {
        int node = row0 + lrow;
        float acc[8];
#pragma unroll
        for (int i = 0; i < 8; ++i) acc[i] = 0.f;
        if (node < n) {
            int start = off[node];
            int cnt = deg[node];
            int s[8];
            float w[8];
#pragma unroll
            for (int t = 0; t < 8; ++t) {
                s[t] = 0; w[t] = 0.f;
                if (t < cnt) {
                    unsigned m = ecsr[start + t];
                    s[t] = (int)(m & 0xFFFFu);
                    w[t] = b2f((unsigned short)(m >> 16));
                }
            }
            for (int bb = 0; bb < cnt; bb += 8) {
                int s2[8];
                float w2[8];
#pragma unroll
                for (int t = 0; t < 8; ++t) {
                    int e = bb + 8 + t;
                    s2[t] = 0; w2[t] = 0.f;
                    if (e < cnt) {
                        unsigned m = ecsr[start + e];
                        s2[t] = (int)(m & 0xFFFFu);
                        w2[t] = b2f((unsigned short)(m >> 16));
                    }
                }
                uint4 u[8];
#pragma unroll
                for (int t = 0; t < 8; ++t)
                    u[t] = *(const uint4*)(hprev + (long)s[t] * JK_DIM + cl * 8);
#pragma unroll
                for (int t = 0; t < 8; ++t) {
                    acc[0] += blo(u[t].x) * w[t];
                    acc[1] += bhi(u[t].x) * w[t];
                    acc[2] += blo(u[t].y) * w[t];
                    acc[3] += bhi(u[t].y) * w[t];
                    acc[4] += blo(u[t].z) * w[t];
                    acc[5] += bhi(u[t].z) * w[t];
                    acc[6] += blo(u[t].w) * w[t];
                    acc[7] += bhi(u[t].w) * w[t];
                }
#pragma unroll
                for (int t = 0; t < 8; ++t) { s[t] = s2[t]; w[t] = w2[t]; }
            }
        }
        uint4 o;
        o.x = pack2(acc[0], acc[1]);
        o.y = pack2(acc[2], acc[3]);
        o.z = pack2(acc[4], acc[5]);
        o.w = pack2(acc[6], acc[7]);
        *(uint4*)(Hs + lrow * HP + cl * 8) = o;
    }
    __syncthreads();
    int wave = tid >> 6;           // 0..7
    int lane = tid & 63;
    int lr = lane & 15;
    int lk = (lane >> 4) * 8;
    int mi = wave >> 1;            // 0..3 (row fragment)
    int ni0 = (wave & 1) * 2;      // 0 or 2 (col fragment start)
    f32x4 d[2];
    d[0] = (f32x4){0.f, 0.f, 0.f, 0.f};
    d[1] = (f32x4){0.f, 0.f, 0.f, 0.f};
#pragma unroll
    for (int k0 = 0; k0 < 64; k0 += 32) {
        bf16x8 a = *(const bf16x8*)(Hs + (mi * 16 + lr) * HP + k0 + lk);
#pragma unroll
        for (int j = 0; j < 2; ++j) {
            bf16x8 b = *(const bf16x8*)(Wt + ((ni0 + j) * 16 + lr) * HP + k0 + lk);
            d[j] = __builtin_amdgcn_mfma_f32_16x16x32_bf16(a, b, d[j], 0, 0, 0);
        }
    }
    int mbase = mi * 16 + (lane >> 4) * 4;
#pragma unroll
    for (int j = 0; j < 2; ++j) {
        int col = (ni0 + j) * 16 + lr;
        float bv = bias[col];
#pragma unroll
        for (int r = 0; r < 4; ++r) {
            int grow = row0 + mbase + r;
            if (grow < n)
                hout[(long)grow * JK_DIM + col] = f2b(fmaxf(d[j][r] + bv, 0.f));
        }
    }
}

// ---------------------------------------------------------------------------
// Layer 3 + JK fused, all-MFMA, 512 THREADS (1 node/group gather; 8-wave
// fragment split). Phase B: even waves -> out cols 0..31, odd -> 32..47
// (cols>=40 discarded; odd wave's 2nd fragment reads stale in-bounds LDS
// and is dropped — keeps register indexing static).
// ---------------------------------------------------------------------------
__global__ __launch_bounds__(512) void jk_final(
        const unsigned short* __restrict__ hprev,   // h2 (row stride JK_DIM)
        const unsigned* __restrict__ ecsr,
        const int* __restrict__ off, const int* __restrict__ deg,
        const unsigned short* __restrict__ W3T, const float* __restrict__ bias,
        const unsigned short* __restrict__ hcat,    // hcatb base
        const unsigned short* __restrict__ WlinT,   // [48][192] bf16 (rows 40+ = 0)
        const float* __restrict__ blin,
        float* __restrict__ outp, int n) {
    __shared__ unsigned short pool[128 * HP];       // 18432 B
    unsigned short* Hs = pool;                      // phase A gather / phase B As
    unsigned short* Wt = pool + 64 * HP;            // phase A W3T / phase B WL
    int tid = threadIdx.x;
    int row0 = blockIdx.x * 64;
    if (row0 >= n) return;
    for (int i = tid; i < 64 * 8; i += 512) {
        int nn = i >> 3;
        int k8 = (i & 7) * 8;
        *(uint4*)(Wt + nn * HP + k8) = *(const uint4*)(W3T + nn * 64 + k8);
    }
    int cl = tid & 7;
    int lrow = tid >> 3;           // one node per group
    {
        int node = row0 + lrow;
        float acc[8];
#pragma unroll
        for (int i = 0; i < 8; ++i) acc[i] = 0.f;
        if (node < n) {
            int start = off[node];
            int cnt = deg[node];
            int s[8];
            float w[8];
#pragma unroll
            for (int t = 0; t < 8; ++t) {
                s[t] = 0; w[t] = 0.f;
                if (t < cnt) {
                    unsigned m = ecsr[start + t];
                    s[t] = (int)(m & 0xFFFFu);
                    w[t] = b2f((unsigned short)(m >> 16));
                }
            }
            for (int bb = 0; bb < cnt; bb += 8) {
                int s2[8];
                float w2[8];
#pragma unroll
                for (int t = 0; t < 8; ++t) {
                    int e = bb + 8 + t;
                    s2[t] = 0; w2[t] = 0.f;
                    if (e < cnt) {
                        unsigned m = ecsr[start + e];
                        s2[t] = (int)(m & 0xFFFFu);
                        w2[t] = b2f((unsigned short)(m >> 16));
                    }
                }
                uint4 u[8];
#pragma unroll
                for (int t = 0; t < 8; ++t)
                    u[t] = *(const uint4*)(hprev + (long)s[t] * JK_DIM + cl * 8);
#pragma unroll
                for (int t = 0; t < 8; ++t) {
                    acc[0] += blo(u[t].x) * w[t];
                    acc[1] += bhi(u[t].x) * w[t];
                    acc[2] += blo(u[t].y) * w[t];
                    acc[3] += bhi(u[t].y) * w[t];
                    acc[4] += blo(u[t].z) * w[t];
                    acc[5] += bhi(u[t].z) * w[t];
                    acc[6] += blo(u[t].w) * w[t];
                    acc[7] += bhi(u[t].w) * w[t];
                }
#pragma unroll
                for (int t = 0; t < 8; ++t) { s[t] = s2[t]; w[t] = w2[t]; }
            }
        }
        uint4 o;
        o.x = pack2(acc[0], acc[1]);
        o.y = pack2(acc[2], acc[3]);
        o.z = pack2(acc[4], acc[5]);
        o.w = pack2(acc[6], acc[7]);
        *(uint4*)(Hs + lrow * HP + cl * 8) = o;
    }
    __syncthreads();
    // phase-A MFMA: d = (A.h2) @ W3, 8-wave fragment split
    int wave = tid >> 6;
    int lane = tid & 63;
    int lr = lane & 15;
    int lk = (lane >> 4) * 8;
    int mi = wave >> 1;
    int ni0 = (wave & 1) * 2;
    f32x4 d[2];
    d[0] = (f32x4){0.f, 0.f, 0.f, 0.f};
    d[1] = (f32x4){0.f, 0.f, 0.f, 0.f};
#pragma unroll
    for (int k0 = 0; k0 < 64; k0 += 32) {
        bf16x8 a = *(const bf16x8*)(Hs + (mi * 16 + lr) * HP + k0 + lk);
#pragma unroll
        for (int j = 0; j < 2; ++j) {
            bf16x8 b = *(const bf16x8*)(Wt + ((ni0 + j) * 16 + lr) * HP + k0 + lk);
            d[j] = __builtin_amdgcn_mfma_f32_16x16x32_bf16(a, b, d[j], 0, 0, 0);
        }
    }
    int mbase = mi * 16 + (lane >> 4) * 4;
    // ---- phase B: out = h1@WL0 + h2@WL1 + h3@WL2 ----
    unsigned short* As = Hs;
    unsigned short* WL = Wt;
    int nj0 = (wave & 1) ? 2 : 0;  // phase-B col-fragment start (odd j=1 discarded)
    f32x4 acc2[2];
    acc2[0] = (f32x4){0.f, 0.f, 0.f, 0.f};
    acc2[1] = (f32x4){0.f, 0.f, 0.f, 0.f};
    for (int ch = 0; ch < 2; ++ch) {
        int cb = ch * 64;
        __syncthreads();   // prior MFMA reads of pool complete
        for (int i = tid; i < 64 * 8; i += 512) {
            int r = i >> 3;
            int q8 = (i & 7) * 8;
            int grow = row0 + r;
            if (grow >= n) grow = n - 1;
            *(uint4*)(As + r * HP + q8) = *(const uint4*)(hcat + (long)grow * JK_DIM + cb + q8);
        }
        for (int i = tid; i < 48 * 8; i += 512) {
            int c = i >> 3;
            int k8 = (i & 7) * 8;
            *(uint4*)(WL + c * HP + k8) = *(const uint4*)(WlinT + c * JK_DIM + cb + k8);
        }
        __syncthreads();
#pragma unroll
        for (int k0 = 0; k0 < 64; k0 += 32) {
            bf16x8 a = *(const bf16x8*)(As + (mi * 16 + lr) * HP + k0 + lk);
#pragma unroll
            for (int j = 0; j < 2; ++j) {
                bf16x8 b = *(const bf16x8*)(WL + ((nj0 + j) * 16 + lr) * HP + k0 + lk);
                acc2[j] = __builtin_amdgcn_mfma_f32_16x16x32_bf16(a, b, acc2[j], 0, 0, 0);
            }
        }
    }
    // chunk 2: h3 = relu(d + b3) from regs
    __syncthreads();
#pragma unroll
    for (int j = 0; j < 2; ++j) {
        int col = (ni0 + j) * 16 + lr;
        float bv = bias[col];
#pragma unroll
        for (int r = 0; r < 4; ++r)
            As[(mbase + r) * HP + col] = f2b(fmaxf(d[j][r] + bv, 0.f));
    }
    for (int i = tid; i < 48 * 8; i += 512) {
        int c = i >> 3;
        int k8 = (i & 7) * 8;
        *(uint4*)(WL + c * HP + k8) = *(const uint4*)(WlinT + c * JK_DIM + 128 + k8);
    }
    __syncthreads();
#pragma unroll
    for (int k0 = 0; k0 < 64; k0 += 32) {
        bf16x8 a = *(const bf16x8*)(As + (mi * 16 + lr) * HP + k0 + lk);
#pragma unroll
        for (int j = 0; j < 2; ++j) {
            bf16x8 b = *(const bf16x8*)(WL + ((nj0 + j) * 16 + lr) * HP + k0 + lk);
            acc2[j] = __builtin_amdgcn_mfma_f32_16x16x32_bf16(a, b, acc2[j], 0, 0, 0);
        }
    }
    // epilogue: out[64][40] f32 (cols >= 40 discarded)
#pragma unroll
    for (int j = 0; j < 2; ++j) {
        int col = (nj0 + j) * 16 + lr;
        if (col < OUT_DIM) {
            float bb = blin[col];
#pragma unroll
            for (int r = 0; r < 4; ++r) {
                int grow = row0 + mbase + r;
                if (grow < n)
                    outp[(long)grow * OUT_DIM + col] = acc2[j][r] + bb;
            }
        }
    }
}

// ---------------------------------------------------------------------------
extern "C" void kernel_launch(void* const* d_in, const int* in_sizes, int n_in,
                              void* d_out, int out_size, void* d_ws, size_t ws_size,
                              hipStream_t stream) {
    const float* x    = (const float*)d_in[0];
    const int*   ei   = (const int*)d_in[1];
    const float* ew   = (const float*)d_in[2];
    const float* W1   = (const float*)d_in[3];
    const float* b1   = (const float*)d_in[4];
    const float* W2   = (const float*)d_in[5];
    const float* b2   = (const float*)d_in[6];
    const float* W3   = (const float*)d_in[7];
    const float* b3   = (const float*)d_in[8];
    const float* Wlin = (const float*)d_in[9];
    const float* blin = (const float*)d_in[10];
    float* out = (float*)d_out;

    const int N = in_sizes[0] / 128;   // 50000
    const int E = in_sizes[2];         // 800000
    const int* src = ei;
    const int* dst = ei + E;
    const int PART = (N + 7) / 8;      // 6250 nodes per XCD partition

    // Workspace: linb | hcatb | deg,off,bsum (memset-zeroed) | W*T | ecsr.
    // rank[E] ALIASES hcatb (dead before aggregate #1 writes hcatb).
    char* wsb = (char*)d_ws;
    unsigned short* linb  = (unsigned short*)wsb;   wsb += (long)N * HID * 2;
    unsigned short* hcatb = (unsigned short*)wsb;   wsb += (long)N * JK_DIM * 2;
    char* zbase = wsb;
    int* deg    = (int*)wsb;                        wsb += (long)N * 4;
    int* off    = (int*)wsb;                        wsb += (long)N * 4;
    int* bsum   = (int*)wsb;                        wsb += 256 * 4;
    size_t zbytes = (size_t)(wsb - zbase);
    unsigned short* W1T  = (unsigned short*)wsb;    wsb += 64 * 128 * 2;
    unsigned short* W2T  = (unsigned short*)wsb;    wsb += 64 * 64 * 2;
    unsigned short* W3T  = (unsigned short*)wsb;    wsb += 64 * 64 * 2;
    unsigned short* WlinT = (unsigned short*)wsb;   wsb += 48 * JK_DIM * 2;
    unsigned* ecsr = (unsigned*)wsb;
    unsigned short* rank = hcatb;      // aliased
    int* gctr = bsum;                  // scan global counter (memset-zeroed)

    dim3 blk(256);
    dim3 blk512(512);
    const int nblkN = (N + 255) / 256;     // 196
    dim3 gN(nblkN);
    const int histBlk = 8 * 104;           // 8 partitions x 104 blocks
    dim3 gHist(histBlk + 32);              // +32 transpose blocks
    const int nFill = ((E >> 2) + 255) / 256;  // 782 fill blocks (first)
    const int nGemm = (N + 63) / 64;           // 782 GEMM tiles (after)
    dim3 gFG(nFill + nGemm);
    dim3 gTile((N + 63) / 64);             // 782 tiles
    dim3 gAgg((N + 31) / 32);              // 8 nodes per wave

    unsigned short* h1 = hcatb;            // columns [0,64)   of hcat[N,192]
    unsigned short* h2 = hcatb + HID;      // columns [64,128)

    // ---- zero deg/off/bsum ----
    hipMemsetAsync(zbase, 0, zbytes, stream);

    // ---- hist(+rank) + weight transposes, fused scan ----
    hist_dst<<<gHist, blk, 0, stream>>>(dst, deg, rank, E, PART, histBlk,
                                        W1, W2, W3, Wlin, W1T, W2T, W3T, WlinT);
    scan_fused<<<gN, blk, 0, stream>>>(deg, off, gctr, N);

    // ---- fused atomic-free CSR fill + layer-1 MFMA GEMM ----
    fill_and_gemm<<<gFG, blk, 0, stream>>>(src, dst, ew, off, rank, ecsr, E,
                                           x, W1T, linb, N, nFill);
    aggregate<<<gAgg, blk, 0, stream>>>(linb, ecsr, off, deg, b1, h1, N);

    // ---- layer 2: fused aggregate+transform (512 threads) ----
    agg_transform<<<gTile, blk512, 0, stream>>>(h1, ecsr, off, deg, W2T, b2, h2, N);

    // ---- layer 3 + JK linear, all-MFMA (512 threads) ----
    jk_final<<<gTile, blk512, 0, stream>>>(h2, ecsr, off, deg, W3T, b3,
                                           hcatb, WlinT, blin, out, N);
}

// Round 14
// 228.437 us; speedup vs baseline: 1.0153x; 1.0153x over previous
//
#include <hip/hip_runtime.h>

// Problem constants: N=50000, E=800000, IN=128, HID=64, OUT=40
#define HID 64
#define JK_DIM 192
#define OUT_DIM 40
#define AP 136         // bf16 LDS pitch for 128-wide tiles (272B = 16B-aligned)
#define HP 72          // bf16 LDS pitch for 64-wide tiles (144B = 16B-aligned)

typedef __attribute__((ext_vector_type(8))) short bf16x8;
typedef __attribute__((ext_vector_type(4))) float f32x4;

// bf16 helpers (RNE pack; packed-word unpack via shift/mask)
__device__ inline unsigned short f2b(float f) {
    unsigned u = __float_as_uint(f);
    unsigned r = u + 0x7FFF + ((u >> 16) & 1);
    return (unsigned short)(r >> 16);
}
__device__ inline float b2f(unsigned short u) {
    return __uint_as_float(((unsigned)u) << 16);
}
__device__ inline float blo(unsigned u) { return __uint_as_float(u << 16); }
__device__ inline float bhi(unsigned u) { return __uint_as_float(u & 0xFFFF0000u); }
__device__ inline unsigned pack2(float a, float b) {
    return (unsigned)f2b(a) | ((unsigned)f2b(b) << 16);
}

// ---------------------------------------------------------------------------
// hist_gemm: co-schedules THREE independent jobs (none depends on another):
//   blocks [0, nGemm)                  -> layer-1 GEMM tiles (lin1 = x@W1),
//                                         W1 staged f32->bf16T in LDS directly
//   blocks [nGemm, nGemm+histBlk)      -> XCD-partitioned histogram + rank
//   blocks [nGemm+histBlk, +32)        -> bf16 transposes W2T/W3T/WlinT
// gemm1 was previously serialized BEHIND hist+scan despite not needing CSR;
// this hides its ~20us under hist's ~30us.
// ---------------------------------------------------------------------------
__global__ __launch_bounds__(256) void hist_gemm(
        const int* __restrict__ dst, int* __restrict__ deg,
        unsigned short* __restrict__ rank, int E, int part,
        int nGemm, int histBlk,
        const float* __restrict__ x, const float* __restrict__ W1,
        unsigned short* __restrict__ linb, int n,
        const float* __restrict__ W2, const float* __restrict__ W3,
        const float* __restrict__ Wlin,
        unsigned short* __restrict__ W2T, unsigned short* __restrict__ W3T,
        unsigned short* __restrict__ WlinT) {
    __shared__ unsigned short Ah[64 * AP];
    __shared__ unsigned short Wt[64 * AP];
    int tid = threadIdx.x;
    int bid = blockIdx.x;
    if (bid >= nGemm + histBlk) {
        // ---- transpose branch (W2T/W3T/WlinT; W1 handled inside gemm) ----
        int base = (bid - nGemm - histBlk) * 256 + tid;
        int stride = 32 * 256;
        for (int i = base; i < 64 * 64; i += stride) {
            int nn = i >> 6, k = i & 63;
            W2T[i] = f2b(W2[k * 64 + nn]);
            W3T[i] = f2b(W3[k * 64 + nn]);
        }
        for (int i = base; i < 48 * JK_DIM; i += stride) {
            int c = i / JK_DIM, k = i - c * JK_DIM;
            WlinT[i] = (c < OUT_DIM) ? f2b(Wlin[k * OUT_DIM + c]) : (unsigned short)0;
        }
        return;
    }
    if (bid >= nGemm) {
        // ---- histogram branch ----
        int hb = bid - nGemm;
        int p = hb & 7;
        int hbid = hb >> 3;
        int nblk = histBlk >> 3;
        int lo = p * part, hi = lo + part;
        int E4 = E >> 2;
        for (int q = hbid * 256 + tid; q < E4; q += nblk * 256) {
            int4 d4 = ((const int4*)dst)[q];
            int e = q * 4;
            if (d4.x >= lo && d4.x < hi) rank[e + 0] = (unsigned short)atomicAdd(&deg[d4.x], 1);
            if (d4.y >= lo && d4.y < hi) rank[e + 1] = (unsigned short)atomicAdd(&deg[d4.y], 1);
            if (d4.z >= lo && d4.z < hi) rank[e + 2] = (unsigned short)atomicAdd(&deg[d4.z], 1);
            if (d4.w >= lo && d4.w < hi) rank[e + 3] = (unsigned short)atomicAdd(&deg[d4.w], 1);
        }
        if (hbid == 0 && tid < (E & 3)) {
            int e = (E & ~3) + tid;
            int d = dst[e];
            if (d >= lo && d < hi) rank[e] = (unsigned short)atomicAdd(&deg[d], 1);
        }
        return;
    }
    // ---- gemm branch: lin1 = x[64x128] @ W1[128x64] via MFMA ----
    int row0 = bid * 64;
    if (row0 >= n) return;
    for (int i = tid; i < 64 * 32; i += 256) {
        int r = i >> 5;
        int c4 = (i & 31) * 4;
        int grow = row0 + r;
        if (grow >= n) grow = n - 1;
        float4 v = *(const float4*)(x + (long)grow * 128 + c4);
        ushort4 o;
        o.x = f2b(v.x); o.y = f2b(v.y); o.z = f2b(v.z); o.w = f2b(v.w);
        *(ushort4*)(Ah + r * AP + c4) = o;
    }
    // stage W1^T bf16 directly from f32 (no dependency on transpose blocks)
    for (int i = tid; i < 128 * 16; i += 256) {
        int k = i >> 4;
        int n4 = (i & 15) * 4;
        float4 v = *(const float4*)(W1 + (long)k * 64 + n4);
        Wt[(n4 + 0) * AP + k] = f2b(v.x);
        Wt[(n4 + 1) * AP + k] = f2b(v.y);
        Wt[(n4 + 2) * AP + k] = f2b(v.z);
        Wt[(n4 + 3) * AP + k] = f2b(v.w);
    }
    __syncthreads();

    int wave = tid >> 6;
    int lane = tid & 63;
    int lr = lane & 15;
    int lk = (lane >> 4) * 8;
    f32x4 acc[4];
#pragma unroll
    for (int nf = 0; nf < 4; ++nf) acc[nf] = (f32x4){0.f, 0.f, 0.f, 0.f};
#pragma unroll
    for (int k0 = 0; k0 < 128; k0 += 32) {
        bf16x8 a = *(const bf16x8*)(Ah + (wave * 16 + lr) * AP + k0 + lk);
#pragma unroll
        for (int nf = 0; nf < 4; ++nf) {
            bf16x8 b = *(const bf16x8*)(Wt + (nf * 16 + lr) * AP + k0 + lk);
            acc[nf] = __builtin_amdgcn_mfma_f32_16x16x32_bf16(a, b, acc[nf], 0, 0, 0);
        }
    }
    int mbase = wave * 16 + (lane >> 4) * 4;
#pragma unroll
    for (int nf = 0; nf < 4; ++nf) {
#pragma unroll
        for (int r = 0; r < 4; ++r) {
            int grow = row0 + mbase + r;
            if (grow < n)
                linb[(long)grow * HID + nf * 16 + lr] = f2b(acc[nf][r]);
        }
    }
}

// ---------------------------------------------------------------------------
// Single-pass scan: block-local prefix + one atomicAdd per block for the base.
// ---------------------------------------------------------------------------
__global__ __launch_bounds__(256) void scan_fused(const int* __restrict__ deg,
                                                  int* __restrict__ off,
                                                  int* __restrict__ gctr, int n) {
    __shared__ int tmp[256];
    __shared__ int base;
    int i = blockIdx.x * 256 + threadIdx.x;
    int v = (i < n) ? deg[i] : 0;
    tmp[threadIdx.x] = v;
    __syncthreads();
    for (int d = 1; d < 256; d <<= 1) {
        int t = (threadIdx.x >= d) ? tmp[threadIdx.x - d] : 0;
        __syncthreads();
        tmp[threadIdx.x] += t;
        __syncthreads();
    }
    if (threadIdx.x == 255) base = atomicAdd(gctr, tmp[255]);
    __syncthreads();
    if (i < n) off[i] = base + tmp[threadIdx.x] - v;
}

// ---------------------------------------------------------------------------
// Standalone atomic-free CSR fill: slot = off[dst] + rank. One int4/thread.
// ---------------------------------------------------------------------------
__global__ __launch_bounds__(256) void fill_csr(
        const int* __restrict__ src, const int* __restrict__ dst,
        const float* __restrict__ ew, const int* __restrict__ off,
        const unsigned short* __restrict__ rank,
        unsigned* __restrict__ ecsr, int E) {
    int tid = threadIdx.x;
    int q = blockIdx.x * 256 + tid;
    int E4 = E >> 2;
    if (q < E4) {
        int4 d4 = ((const int4*)dst)[q];
        int4 s4 = ((const int4*)src)[q];
        float4 wv = ((const float4*)ew)[q];
        ushort4 r4 = ((const ushort4*)rank)[q];
        ecsr[off[d4.x] + r4.x] = (unsigned)s4.x | ((unsigned)f2b(wv.x) << 16);
        ecsr[off[d4.y] + r4.y] = (unsigned)s4.y | ((unsigned)f2b(wv.y) << 16);
        ecsr[off[d4.z] + r4.z] = (unsigned)s4.z | ((unsigned)f2b(wv.z) << 16);
        ecsr[off[d4.w] + r4.w] = (unsigned)s4.w | ((unsigned)f2b(wv.w) << 16);
    }
    if (blockIdx.x == 0 && tid < (E & 3)) {
        int e = (E & ~3) + tid;
        int d = dst[e];
        ecsr[off[d] + rank[e]] = (unsigned)src[e] | ((unsigned)f2b(ew[e]) << 16);
    }
}

// ---------------------------------------------------------------------------
// Aggregate + bias + ReLU (layer 1). 8-lane group per node; 8-deep pipeline.
// ---------------------------------------------------------------------------
__global__ __launch_bounds__(256) void aggregate(const unsigned short* __restrict__ linb,
                                                 const unsigned* __restrict__ ecsr,
                                                 const int* __restrict__ off,
                                                 const int* __restrict__ deg,
                                                 const float* __restrict__ bias,
                                                 unsigned short* __restrict__ hout, int n) {
    int cl = threadIdx.x & 7;
    float4 bLo = *(const float4*)(bias + cl * 8);
    float4 bHi = *(const float4*)(bias + cl * 8 + 4);
    int grp = (blockIdx.x * 256 + threadIdx.x) >> 3;
    int ngrp = (gridDim.x * 256) >> 3;
    for (int node = grp; node < n; node += ngrp) {
        int start = off[node];
        int cnt = deg[node];
        float acc[8];
#pragma unroll
        for (int i = 0; i < 8; ++i) acc[i] = 0.f;

        int s[8];
        float w[8];
#pragma unroll
        for (int t = 0; t < 8; ++t) {
            s[t] = 0; w[t] = 0.f;
            if (t < cnt) {
                unsigned m = ecsr[start + t];
                s[t] = (int)(m & 0xFFFFu);
                w[t] = b2f((unsigned short)(m >> 16));
            }
        }
        for (int bb = 0; bb < cnt; bb += 8) {
            int s2[8];
            float w2[8];
#pragma unroll
            for (int t = 0; t < 8; ++t) {
                int e = bb + 8 + t;
                s2[t] = 0; w2[t] = 0.f;
                if (e < cnt) {
                    unsigned m = ecsr[start + e];
                    s2[t] = (int)(m & 0xFFFFu);
                    w2[t] = b2f((unsigned short)(m >> 16));
                }
            }
            uint4 u[8];
#pragma unroll
            for (int t = 0; t < 8; ++t)
                u[t] = *(const uint4*)(linb + (long)s[t] * HID + cl * 8);
#pragma unroll
            for (int t = 0; t < 8; ++t) {
                acc[0] += blo(u[t].x) * w[t];
                acc[1] += bhi(u[t].x) * w[t];
                acc[2] += blo(u[t].y) * w[t];
                acc[3] += bhi(u[t].y) * w[t];
                acc[4] += blo(u[t].z) * w[t];
                acc[5] += bhi(u[t].z) * w[t];
                acc[6] += blo(u[t].w) * w[t];
                acc[7] += bhi(u[t].w) * w[t];
            }
#pragma unroll
            for (int t = 0; t < 8; ++t) { s[t] = s2[t]; w[t] = w2[t]; }
        }

        uint4 o;
        o.x = pack2(fmaxf(acc[0] + bLo.x, 0.f), fmaxf(acc[1] + bLo.y, 0.f));
        o.y = pack2(fmaxf(acc[2] + bLo.z, 0.f), fmaxf(acc[3] + bLo.w, 0.f));
        o.z = pack2(fmaxf(acc[4] + bHi.x, 0.f), fmaxf(acc[5] + bHi.y, 0.f));
        o.w = pack2(fmaxf(acc[6] + bHi.z, 0.f), fmaxf(acc[7] + bHi.w, 0.f));
        *(uint4*)(hout + (long)node * JK_DIM + cl * 8) = o;
    }
}

// ---------------------------------------------------------------------------
// Layer 2: h_out = relu((A.h_prev)@W + b). r12 256-thread form (measured
// best; r13's 512-thread variant was neutral-to-worse).
// ---------------------------------------------------------------------------
__global__ __launch_bounds__(256) void agg_transform(
        const unsigned short* __restrict__ hprev,   // row stride JK_DIM
        const unsigned* __restrict__ ecsr,
        const int* __restrict__ off, const int* __restrict__ deg,
        const unsigned short* __restrict__ WT, const float* __restrict__ bias,
        unsigned short* __restrict__ hout, int n) { // row stride JK_DIM
    __shared__ unsigned short Hs[64 * HP];
    __shared__ unsigned short Wt[64 * HP];
    int tid = threadIdx.x;
    int row0 = blockIdx.x * 64;
    if (row0 >= n) return;
    for (int i = tid; i < 64 * 8; i += 256) {
        int nn = i >> 3;
        int k8 = (i & 7) * 8;
        *(uint4*)(Wt + nn * HP + k8) = *(const uint4*)(WT + nn * 64 + k8);
    }
    int cl = tid & 7;
    int g0 = tid >> 3;
    for (int gi = 0; gi < 2; ++gi) {
        int lrow = g0 + gi * 32;
        int node = row0 + lrow;
        float acc[8];
#pragma unroll
        for (int i = 0; i < 8; ++i) acc[i] = 0.f;
        if (node < n) {
            int start = off[node];
            int cnt = deg[node];
            int s[8];
            float w[8];
#pragma unroll
            for (int t = 0; t < 8; ++t) {
                s[t] = 0; w[t] = 0.f;
                if (t < cnt) {
                    unsigned m = ecsr[start + t];
                    s[t] = (int)(m & 0xFFFFu);
                    w[t] = b2f((unsigned short)(m >> 16));
                }
            }
            for (int bb = 0; bb < cnt; bb += 8) {
                int s2[8];
                float w2[8];
#pragma unroll
                for (int t = 0; t < 8; ++t) {
                    int e = bb + 8 + t;
                    s2[t] = 0; w2[t] = 0.f;
                    if (e < cnt) {
                        unsigned m = ecsr[start + e];
                        s2[t] = (int)(m & 0xFFFFu);
                        w2[t] = b2f((unsigned short)(m >> 16));
                    }
                }
                uint4 u[8];
#pragma unroll
                for (int t = 0; t < 8; ++t)
                    u[t] = *(const uint4*)(hprev + (long)s[t] * JK_DIM + cl * 8);
#pragma unroll
                for (int t = 0; t < 8; ++t) {
                    acc[0] += blo(u[t].x) * w[t];
                    acc[1] += bhi(u[t].x) * w[t];
                    acc[2] += blo(u[t].y) * w[t];
                    acc[3] += bhi(u[t].y) * w[t];
                    acc[4] += blo(u[t].z) * w[t];
                    acc[5] += bhi(u[t].z) * w[t];
                    acc[6] += blo(u[t].w) * w[t];
                    acc[7] += bhi(u[t].w) * w[t];
                }
#pragma unroll
                for (int t = 0; t < 8; ++t) { s[t] = s2[t]; w[t] = w2[t]; }
            }
        }
        uint4 o;
        o.x = pack2(acc[0], acc[1]);
        o.y = pack2(acc[2], acc[3]);
        o.z = pack2(acc[4], acc[5]);
        o.w = pack2(acc[6], acc[7]);
        *(uint4*)(Hs + lrow * HP + cl * 8) = o;
    }
    __syncthreads();
    int wave = tid >> 6;
    int lane = tid & 63;
    int lr = lane & 15;
    int lk = (lane >> 4) * 8;
    f32x4 d[4];
#pragma unroll
    for (int nf = 0; nf < 4; ++nf) d[nf] = (f32x4){0.f, 0.f, 0.f, 0.f};
#pragma unroll
    for (int k0 = 0; k0 < 64; k0 += 32) {
        bf16x8 a = *(const bf16x8*)(Hs + (wave * 16 + lr) * HP + k0 + lk);
#pragma unroll
        for (int nf = 0; nf < 4; ++nf) {
            bf16x8 b = *(const bf16x8*)(Wt + (nf * 16 + lr) * HP + k0 + lk);
            d[nf] = __builtin_amdgcn_mfma_f32_16x16x32_bf16(a, b, d[nf], 0, 0, 0);
        }
    }
    int mbase = wave * 16 + (lane >> 4) * 4;
#pragma unroll
    for (int nf = 0; nf < 4; ++nf) {
        float bv = bias[nf * 16 + lr];
#pragma unroll
        for (int r = 0; r < 4; ++r) {
            int grow = row0 + mbase + r;
            if (grow < n)
                hout[(long)grow * JK_DIM + nf * 16 + lr] = f2b(fmaxf(d[nf][r] + bv, 0.f));
        }
    }
}

// ---------------------------------------------------------------------------
// Layer 3 + JK fused, all-MFMA, K-SPLIT phase B (18.4KB LDS, r12 form).
// ---------------------------------------------------------------------------
__global__ __launch_bounds__(256) void jk_final(
        const unsigned short* __restrict__ hprev,   // h2 (row stride JK_DIM)
        const unsigned* __restrict__ ecsr,
        const int* __restrict__ off, const int* __restrict__ deg,
        const unsigned short* __restrict__ W3T, const float* __restrict__ bias,
        const unsigned short* __restrict__ hcat,    // hcatb base
        const unsigned short* __restrict__ WlinT,   // [48][192] bf16 (rows 40+ = 0)
        const float* __restrict__ blin,
        float* __restrict__ outp, int n) {
    __shared__ unsigned short pool[128 * HP];       // 18432 B
    unsigned short* Hs = pool;
    unsigned short* Wt = pool + 64 * HP;
    int tid = threadIdx.x;
    int row0 = blockIdx.x * 64;
    if (row0 >= n) return;
    for (int i = tid; i < 64 * 8; i += 256) {
        int nn = i >> 3;
        int k8 = (i & 7) * 8;
        *(uint4*)(Wt + nn * HP + k8) = *(const uint4*)(W3T + nn * 64 + k8);
    }
    int cl = tid & 7;
    int g0 = tid >> 3;
    for (int gi = 0; gi < 2; ++gi) {
        int lrow = g0 + gi * 32;
        int node = row0 + lrow;
        float acc[8];
#pragma unroll
        for (int i = 0; i < 8; ++i) acc[i] = 0.f;
        if (node < n) {
            int start = off[node];
            int cnt = deg[node];
            int s[8];
            float w[8];
#pragma unroll
            for (int t = 0; t < 8; ++t) {
                s[t] = 0; w[t] = 0.f;
                if (t < cnt) {
                    unsigned m = ecsr[start + t];
                    s[t] = (int)(m & 0xFFFFu);
                    w[t] = b2f((unsigned short)(m >> 16));
                }
            }
            for (int bb = 0; bb < cnt; bb += 8) {
                int s2[8];
                float w2[8];
#pragma unroll
                for (int t = 0; t < 8; ++t) {
                    int e = bb + 8 + t;
                    s2[t] = 0; w2[t] = 0.f;
                    if (e < cnt) {
                        unsigned m = ecsr[start + e];
                        s2[t] = (int)(m & 0xFFFFu);
                        w2[t] = b2f((unsigned short)(m >> 16));
                    }
                }
                uint4 u[8];
#pragma unroll
                for (int t = 0; t < 8; ++t)
                    u[t] = *(const uint4*)(hprev + (long)s[t] * JK_DIM + cl * 8);
#pragma unroll
                for (int t = 0; t < 8; ++t) {
                    acc[0] += blo(u[t].x) * w[t];
                    acc[1] += bhi(u[t].x) * w[t];
                    acc[2] += blo(u[t].y) * w[t];
                    acc[3] += bhi(u[t].y) * w[t];
                    acc[4] += blo(u[t].z) * w[t];
                    acc[5] += bhi(u[t].z) * w[t];
                    acc[6] += blo(u[t].w) * w[t];
                    acc[7] += bhi(u[t].w) * w[t];
                }
#pragma unroll
                for (int t = 0; t < 8; ++t) { s[t] = s2[t]; w[t] = w2[t]; }
            }
        }
        uint4 o;
        o.x = pack2(acc[0], acc[1]);
        o.y = pack2(acc[2], acc[3]);
        o.z = pack2(acc[4], acc[5]);
        o.w = pack2(acc[6], acc[7]);
        *(uint4*)(Hs + lrow * HP + cl * 8) = o;
    }
    __syncthreads();
    int wave = tid >> 6;
    int lane = tid & 63;
    int lr = lane & 15;
    int lk = (lane >> 4) * 8;
    f32x4 d[4];
#pragma unroll
    for (int nf = 0; nf < 4; ++nf) d[nf] = (f32x4){0.f, 0.f, 0.f, 0.f};
#pragma unroll
    for (int k0 = 0; k0 < 64; k0 += 32) {
        bf16x8 a = *(const bf16x8*)(Hs + (wave * 16 + lr) * HP + k0 + lk);
#pragma unroll
        for (int nf = 0; nf < 4; ++nf) {
            bf16x8 b = *(const bf16x8*)(Wt + (nf * 16 + lr) * HP + k0 + lk);
            d[nf] = __builtin_amdgcn_mfma_f32_16x16x32_bf16(a, b, d[nf], 0, 0, 0);
        }
    }
    int mbase = wave * 16 + (lane >> 4) * 4;
    unsigned short* As = Hs;
    unsigned short* WL = Wt;
    f32x4 acc2[3];
#pragma unroll
    for (int nf = 0; nf < 3; ++nf) acc2[nf] = (f32x4){0.f, 0.f, 0.f, 0.f};
    for (int ch = 0; ch < 2; ++ch) {
        int cb = ch * 64;
        __syncthreads();
        for (int i = tid; i < 64 * 8; i += 256) {
            int r = i >> 3;
            int q8 = (i & 7) * 8;
            int grow = row0 + r;
            if (grow >= n) grow = n - 1;
            *(uint4*)(As + r * HP + q8) = *(const uint4*)(hcat + (long)grow * JK_DIM + cb + q8);
        }
        for (int i = tid; i < 48 * 8; i += 256) {
            int c = i >> 3;
            int k8 = (i & 7) * 8;
            *(uint4*)(WL + c * HP + k8) = *(const uint4*)(WlinT + c * JK_DIM + cb + k8);
        }
        __syncthreads();
#pragma unroll
        for (int k0 = 0; k0 < 64; k0 += 32) {
            bf16x8 a = *(const bf16x8*)(As + (wave * 16 + lr) * HP + k0 + lk);
#pragma unroll
            for (int nf = 0; nf < 3; ++nf) {
                bf16x8 b = *(const bf16x8*)(WL + (nf * 16 + lr) * HP + k0 + lk);
                acc2[nf] = __builtin_amdgcn_mfma_f32_16x16x32_bf16(a, b, acc2[nf], 0, 0, 0);
            }
        }
    }
    __syncthreads();
#pragma unroll
    for (int nf = 0; nf < 4; ++nf) {
        float bv = bias[nf * 16 + lr];
#pragma unroll
        for (int r = 0; r < 4; ++r)
            As[(mbase + r) * HP + nf * 16 + lr] = f2b(fmaxf(d[nf][r] + bv, 0.f));
    }
    for (int i = tid; i < 48 * 8; i += 256) {
        int c = i >> 3;
        int k8 = (i & 7) * 8;
        *(uint4*)(WL + c * HP + k8) = *(const uint4*)(WlinT + c * JK_DIM + 128 + k8);
    }
    __syncthreads();
#pragma unroll
    for (int k0 = 0; k0 < 64; k0 += 32) {
        bf16x8 a = *(const bf16x8*)(As + (wave * 16 + lr) * HP + k0 + lk);
#pragma unroll
        for (int nf = 0; nf < 3; ++nf) {
            bf16x8 b = *(const bf16x8*)(WL + (nf * 16 + lr) * HP + k0 + lk);
            acc2[nf] = __builtin_amdgcn_mfma_f32_16x16x32_bf16(a, b, acc2[nf], 0, 0, 0);
        }
    }
#pragma unroll
    for (int nf = 0; nf < 3; ++nf) {
        int col = nf * 16 + lr;
        if (col < OUT_DIM) {
            float bb = blin[col];
#pragma unroll
            for (int r = 0; r < 4; ++r) {
                int grow = row0 + mbase + r;
                if (grow < n)
                    outp[(long)grow * OUT_DIM + col] = acc2[nf][r] + bb;
            }
        }
    }
}

// ---------------------------------------------------------------------------
extern "C" void kernel_launch(void* const* d_in, const int* in_sizes, int n_in,
                              void* d_out, int out_size, void* d_ws, size_t ws_size,
                              hipStream_t stream) {
    const float* x    = (const float*)d_in[0];
    const int*   ei   = (const int*)d_in[1];
    const float* ew   = (const float*)d_in[2];
    const float* W1   = (const float*)d_in[3];
    const float* b1   = (const float*)d_in[4];
    const float* W2   = (const float*)d_in[5];
    const float* b2   = (const float*)d_in[6];
    const float* W3   = (const float*)d_in[7];
    const float* b3   = (const float*)d_in[8];
    const float* Wlin = (const float*)d_in[9];
    const float* blin = (const float*)d_in[10];
    float* out = (float*)d_out;

    const int N = in_sizes[0] / 128;   // 50000
    const int E = in_sizes[2];         // 800000
    const int* src = ei;
    const int* dst = ei + E;
    const int PART = (N + 7) / 8;      // 6250 nodes per XCD partition

    // Workspace: linb | hcatb | deg,off,bsum (memset-zeroed) | W2T,W3T,WlinT
    // | ecsr.  rank[E] ALIASES hcatb (dead before aggregate #1 writes hcatb).
    char* wsb = (char*)d_ws;
    unsigned short* linb  = (unsigned short*)wsb;   wsb += (long)N * HID * 2;
    unsigned short* hcatb = (unsigned short*)wsb;   wsb += (long)N * JK_DIM * 2;
    char* zbase = wsb;
    int* deg    = (int*)wsb;                        wsb += (long)N * 4;
    int* off    = (int*)wsb;                        wsb += (long)N * 4;
    int* bsum   = (int*)wsb;                        wsb += 256 * 4;
    size_t zbytes = (size_t)(wsb - zbase);
    unsigned short* W2T  = (unsigned short*)wsb;    wsb += 64 * 64 * 2;
    unsigned short* W3T  = (unsigned short*)wsb;    wsb += 64 * 64 * 2;
    unsigned short* WlinT = (unsigned short*)wsb;   wsb += 48 * JK_DIM * 2;
    unsigned* ecsr = (unsigned*)wsb;
    unsigned short* rank = hcatb;      // aliased
    int* gctr = bsum;                  // scan global counter (memset-zeroed)

    dim3 blk(256);
    const int nblkN = (N + 255) / 256;     // 196
    dim3 gN(nblkN);
    const int nGemm = (N + 63) / 64;       // 782 gemm tiles (first)
    const int histBlk = 8 * 104;           // 832 hist blocks (after)
    dim3 gHG(nGemm + histBlk + 32);        // + 32 transpose blocks
    const int nFill = ((E >> 2) + 255) / 256;  // 782 fill blocks
    dim3 gFill(nFill);
    dim3 gTile((N + 63) / 64);             // 782 tiles
    dim3 gAgg((N + 31) / 32);              // 8 nodes per wave

    unsigned short* h1 = hcatb;            // columns [0,64)   of hcat[N,192]
    unsigned short* h2 = hcatb + HID;      // columns [64,128)

    // ---- zero deg/off/bsum ----
    hipMemsetAsync(zbase, 0, zbytes, stream);

    // ---- co-scheduled: gemm1 (independent of CSR) + hist(+rank) + transposes
    hist_gemm<<<gHG, blk, 0, stream>>>(dst, deg, rank, E, PART, nGemm, histBlk,
                                       x, W1, linb, N, W2, W3, Wlin,
                                       W2T, W3T, WlinT);
    scan_fused<<<gN, blk, 0, stream>>>(deg, off, gctr, N);
    fill_csr<<<gFill, blk, 0, stream>>>(src, dst, ew, off, rank, ecsr, E);

    aggregate<<<gAgg, blk, 0, stream>>>(linb, ecsr, off, deg, b1, h1, N);
    agg_transform<<<gTile, blk, 0, stream>>>(h1, ecsr, off, deg, W2T, b2, h2, N);
    jk_final<<<gTile, blk, 0, stream>>>(h2, ecsr, off, deg, W3T, b3,
                                        hcatb, WlinT, blin, out, N);
}